// Round 1
// baseline (2517.152 us; speedup 1.0000x reference)
//
#include <hip/hip_runtime.h>

#define T 2048
#define HID 4096
#define NH 32
#define NKV 8
#define HD 128
#define QKV_OUT ((NH + 2*NKV) * HD)   // 6144
#define SCALING 0.08838834764831843f  // 128^-0.5

typedef __attribute__((ext_vector_type(8))) short bfrag;   // 8 bf16
typedef __attribute__((ext_vector_type(4))) float ffrag;   // 4 f32 acc

__device__ __forceinline__ short f2bf(float f) {
  unsigned u = __builtin_bit_cast(unsigned, f);
  u += 0x7fffu + ((u >> 16) & 1u);   // RNE; exact for |int| < 256 anyway
  return (short)(u >> 16);
}

// ---------------- a_sum: per-row int sum of q_act ----------------
__global__ __launch_bounds__(256)
void asum_kernel(const int* __restrict__ qact, float* __restrict__ a_sum) {
  __shared__ int red[256];
  const int t = blockIdx.x, tid = threadIdx.x;
  const int4* row = (const int4*)(qact + (size_t)t * HID);
  int s = 0;
#pragma unroll
  for (int i = 0; i < 4; i++) {
    int4 v = row[tid + 256 * i];
    s += v.x + v.y + v.z + v.w;
  }
  red[tid] = s; __syncthreads();
  for (int off = 128; off > 0; off >>= 1) {
    if (tid < off) red[tid] += red[tid + off];
    __syncthreads();
  }
  if (tid == 0) a_sum[t] = (float)red[0];
}

// ---------------- W4A8 GEMM: C[M,N] = sa*sw*(A·W^T - zw*asum) ----------------
// A: M x K row-major (int32 or bf16-as-short), W: N x K row-major int32 (0..15).
// bf16 MFMA is EXACT here (small ints, fp32 acc < 2^24).
// 128x128 tile, BK=32, 4 waves (2x2), each wave 64x64 = 4x4 MFMA 16x16x32.
template<int ABYTES>
__global__ __launch_bounds__(256)
void gemm_w4a8(const void* __restrict__ Av, const int* __restrict__ W,
               const float* __restrict__ s_a, const float* __restrict__ asum,
               const float* __restrict__ s_w, const float* __restrict__ z_w,
               float* __restrict__ C, int M, int N, int K) {
  // pitch 40 shorts = 80 B: fragment b128 reads hit every bank exactly 8x (floor)
  __shared__ __align__(16) short As[128 * 40];
  __shared__ __align__(16) short Bs[128 * 40];
  const int tid = threadIdx.x;
  const int lane = tid & 63;
  const int quad = lane >> 4, l15 = lane & 15;
  const int wave = tid >> 6;
  const int wm = (wave >> 1) * 64, wn = (wave & 1) * 64;
  const int bm = blockIdx.y * 128, bn = blockIdx.x * 128;

  ffrag acc[4][4];
#pragma unroll
  for (int mi = 0; mi < 4; mi++)
#pragma unroll
    for (int ni = 0; ni < 4; ni++)
      acc[mi][ni] = (ffrag){0.f, 0.f, 0.f, 0.f};

  for (int k0 = 0; k0 < K; k0 += 32) {
    if constexpr (ABYTES == 4) {
      const int* A = (const int*)Av;
#pragma unroll
      for (int i = 0; i < 4; i++) {
        int e = tid + 256 * i;          // int4 index over 128x32 tile
        int r = e >> 3, c = e & 7;
        int4 v = *(const int4*)(A + (size_t)(bm + r) * K + k0 + c * 4);
        short4 h;
        h.x = f2bf((float)v.x); h.y = f2bf((float)v.y);
        h.z = f2bf((float)v.z); h.w = f2bf((float)v.w);
        *(short4*)&As[r * 40 + c * 4] = h;
      }
    } else {
      const short* A = (const short*)Av;  // bf16 activations
#pragma unroll
      for (int i = 0; i < 2; i++) {
        int e = tid + 256 * i;          // short8 index
        int r = e >> 2, c = e & 3;
        bfrag v = *(const bfrag*)(A + (size_t)(bm + r) * K + k0 + c * 8);
        *(bfrag*)&As[r * 40 + c * 8] = v;
      }
    }
#pragma unroll
    for (int i = 0; i < 4; i++) {
      int e = tid + 256 * i;
      int r = e >> 3, c = e & 7;
      int4 v = *(const int4*)(W + (size_t)(bn + r) * K + k0 + c * 4);
      short4 h;
      h.x = f2bf((float)v.x); h.y = f2bf((float)v.y);
      h.z = f2bf((float)v.z); h.w = f2bf((float)v.w);
      *(short4*)&Bs[r * 40 + c * 4] = h;
    }
    __syncthreads();

    bfrag af[4], bfv[4];
#pragma unroll
    for (int mi = 0; mi < 4; mi++)
      af[mi] = *(const bfrag*)&As[(wm + mi * 16 + l15) * 40 + quad * 8];
#pragma unroll
    for (int ni = 0; ni < 4; ni++)
      bfv[ni] = *(const bfrag*)&Bs[(wn + ni * 16 + l15) * 40 + quad * 8];
#pragma unroll
    for (int mi = 0; mi < 4; mi++)
#pragma unroll
      for (int ni = 0; ni < 4; ni++)
        acc[mi][ni] = __builtin_amdgcn_mfma_f32_16x16x32_bf16(
            af[mi], bfv[ni], acc[mi][ni], 0, 0, 0);
    __syncthreads();
  }

  // epilogue: C/D layout col=lane&15, row=(lane>>4)*4+reg (verified m89/m91)
#pragma unroll
  for (int mi = 0; mi < 4; mi++) {
    int row0 = bm + wm + mi * 16 + quad * 4;
#pragma unroll
    for (int r = 0; r < 4; r++) {
      int row = row0 + r;
      float sa = s_a[row], av = asum[row];
#pragma unroll
      for (int ni = 0; ni < 4; ni++) {
        int col = bn + wn + ni * 16 + l15;
        C[(size_t)row * N + col] = (sa * s_w[col]) * (acc[mi][ni][r] - z_w[col] * av);
      }
    }
  }
}

// ---------------- RoPE (in-place on fp32 qkv, q heads + k heads) ----------------
__global__ __launch_bounds__(64)
void rope_kernel(float* __restrict__ qkv, const int* __restrict__ positions) {
  const int b = blockIdx.x;
  const int t = b / (NH + NKV);
  const int h = b % (NH + NKV);          // k head j lives at (NH+j)*HD = h*HD
  float* base = qkv + (size_t)t * QKV_OUT + (size_t)h * HD;
  const int i = threadIdx.x;             // 0..63 = rotation pair index
  float inv = exp2f(-0.20762050593046014f * (float)i);  // 10000^(-i/64)
  float f = (float)positions[t] * inv;
  float s, c;
  sincosf(f, &s, &c);
  float x1 = base[i], x2 = base[i + 64];
  base[i]      = x1 * c - x2 * s;
  base[i + 64] = x2 * c + x1 * s;
}

// ---------------- fp32 flash attention (causal, GQA) ----------------
// Block: head h, 64 q rows. Thread (qi=tid>>2, g=tid&3) owns row q0+qi,
// dims d = 16j + 4g + jj (conflict-free b128 LDS reads, 16-way broadcast free).
__global__ __launch_bounds__(256)
void attn_kernel(const float* __restrict__ qkv, float* __restrict__ attn) {
  __shared__ __align__(16) float Ks[32 * HD];
  __shared__ __align__(16) float Vs[32 * HD];
  __shared__ float Ps[64 * 33];
  const int h = blockIdx.y;
  const int q0 = blockIdx.x * 64;
  const int kvh = h >> 2;                // REP = 4
  const int tid = threadIdx.x;
  const int qi = tid >> 2, g = tid & 3;
  const int t = q0 + qi;

  const float* qrow = qkv + (size_t)t * QKV_OUT + (size_t)h * HD;
  float4 q4[8];
#pragma unroll
  for (int j = 0; j < 8; j++)
    q4[j] = *(const float4*)(qrow + j * 16 + g * 4);

  float4 acc4[8];
#pragma unroll
  for (int j = 0; j < 8; j++) acc4[j] = make_float4(0.f, 0.f, 0.f, 0.f);
  float m_i = -__builtin_inff(), l_i = 0.f;

  const float* Kbase = qkv + (size_t)NH * HD + (size_t)kvh * HD;
  const float* Vbase = qkv + (size_t)(NH + NKV) * HD + (size_t)kvh * HD;
  const int ktiles = (q0 >> 5) + 2;      // keys 0 .. q0+63

  for (int kt = 0; kt < ktiles; kt++) {
    const int k0 = kt << 5;
#pragma unroll
    for (int i = 0; i < 4; i++) {
      int e = tid + 256 * i;
      int ki = e >> 5, d = e & 31;
      *(float4*)&Ks[ki * HD + d * 4] = *(const float4*)(Kbase + (size_t)(k0 + ki) * QKV_OUT + d * 4);
      *(float4*)&Vs[ki * HD + d * 4] = *(const float4*)(Vbase + (size_t)(k0 + ki) * QKV_OUT + d * 4);
    }
    __syncthreads();

    float sv[8];
#pragma unroll
    for (int ki = 0; ki < 32; ki++) {
      float s = 0.f;
      const float* kr = &Ks[ki * HD + g * 4];
#pragma unroll
      for (int j = 0; j < 8; j++) {
        float4 kv = *(const float4*)(kr + j * 16);
        s += q4[j].x * kv.x + q4[j].y * kv.y + q4[j].z * kv.z + q4[j].w * kv.w;
      }
      s += __shfl_xor(s, 1);             // combine 4 owner threads of this row
      s += __shfl_xor(s, 2);
      if ((ki >> 3) == g)
        sv[ki & 7] = (k0 + ki <= t) ? s * SCALING : -__builtin_inff();
    }
    // online softmax stats (replicated per 4 owner threads; identical values)
    float mt = -__builtin_inff();
#pragma unroll
    for (int u = 0; u < 8; u++) mt = fmaxf(mt, sv[u]);
    mt = fmaxf(mt, __shfl_xor(mt, 1));
    mt = fmaxf(mt, __shfl_xor(mt, 2));
    float m_new = fmaxf(m_i, mt);        // finite from tile 0 (key 0 unmasked)
    float alpha = expf(m_i - m_new);
    float ls = 0.f;
#pragma unroll
    for (int u = 0; u < 8; u++) {
      float p = expf(sv[u] - m_new);
      ls += p;
      Ps[qi * 33 + g * 8 + u] = p;
    }
    ls += __shfl_xor(ls, 1);
    ls += __shfl_xor(ls, 2);
    l_i = l_i * alpha + ls;
    m_i = m_new;
#pragma unroll
    for (int j = 0; j < 8; j++) {
      acc4[j].x *= alpha; acc4[j].y *= alpha; acc4[j].z *= alpha; acc4[j].w *= alpha;
    }
    __syncthreads();                     // publish Ps
#pragma unroll
    for (int ki = 0; ki < 32; ki++) {
      float p = Ps[qi * 33 + ki];
      const float* vr = &Vs[ki * HD + g * 4];
#pragma unroll
      for (int j = 0; j < 8; j++) {
        float4 vv = *(const float4*)(vr + j * 16);
        acc4[j].x += p * vv.x; acc4[j].y += p * vv.y;
        acc4[j].z += p * vv.z; acc4[j].w += p * vv.w;
      }
    }
    __syncthreads();                     // before restaging K/V
  }

  const float invl = 1.f / l_i;
  float* orow = attn + (size_t)t * HID + (size_t)h * HD;
#pragma unroll
  for (int j = 0; j < 8; j++) {
    float4 o = make_float4(acc4[j].x * invl, acc4[j].y * invl,
                           acc4[j].z * invl, acc4[j].w * invl);
    *(float4*)(orow + j * 16 + g * 4) = o;
  }
}

// ---------------- dynamic quant with sum (per row) ----------------
__global__ __launch_bounds__(256)
void quant_kernel(const float* __restrict__ x, short* __restrict__ q2,
                  float* __restrict__ s2, float* __restrict__ sum2) {
  __shared__ float red[256];
  const int t = blockIdx.x, tid = threadIdx.x;
  const float* row = x + (size_t)t * HID;
  float4 v[4];
  float m = 0.f;
#pragma unroll
  for (int i = 0; i < 4; i++) {
    v[i] = *(const float4*)(row + (tid + 256 * i) * 4);
    m = fmaxf(m, fmaxf(fmaxf(fabsf(v[i].x), fabsf(v[i].y)),
                       fmaxf(fabsf(v[i].z), fabsf(v[i].w))));
  }
  red[tid] = m; __syncthreads();
  for (int off = 128; off > 0; off >>= 1) {
    if (tid < off) red[tid] = fmaxf(red[tid], red[tid + off]);
    __syncthreads();
  }
  float s = fmaxf(red[0], 1e-8f) / 127.f;
  __syncthreads();                       // before reusing red
  float ssum = 0.f;
#pragma unroll
  for (int i = 0; i < 4; i++) {
    short4 h; float q;
    q = fminf(127.f, fmaxf(-127.f, rintf(v[i].x / s))); ssum += q; h.x = f2bf(q);
    q = fminf(127.f, fmaxf(-127.f, rintf(v[i].y / s))); ssum += q; h.y = f2bf(q);
    q = fminf(127.f, fmaxf(-127.f, rintf(v[i].z / s))); ssum += q; h.z = f2bf(q);
    q = fminf(127.f, fmaxf(-127.f, rintf(v[i].w / s))); ssum += q; h.w = f2bf(q);
    *(short4*)(q2 + (size_t)t * HID + (tid + 256 * i) * 4) = h;
  }
  red[tid] = ssum; __syncthreads();
  for (int off = 128; off > 0; off >>= 1) {
    if (tid < off) red[tid] += red[tid + off];
    __syncthreads();
  }
  if (tid == 0) { s2[t] = s; sum2[t] = red[0]; }
}

// ---------------- launch ----------------
extern "C" void kernel_launch(void* const* d_in, const int* in_sizes, int n_in,
                              void* d_out, int out_size, void* d_ws, size_t ws_size,
                              hipStream_t stream) {
  const int*   positions   = (const int*)d_in[0];
  const int*   q_act       = (const int*)d_in[1];
  const float* act_scale   = (const float*)d_in[2];
  const int*   w_qkv_q     = (const int*)d_in[3];
  const float* w_qkv_scale = (const float*)d_in[4];
  const float* w_qkv_zero  = (const float*)d_in[5];
  const int*   w_o_q       = (const int*)d_in[6];
  const float* w_o_scale   = (const float*)d_in[7];
  const float* w_o_zero    = (const float*)d_in[8];
  float* out = (float*)d_out;

  float* qkv   = (float*)d_ws;                    // T*6144 f32 (50.3 MB)
  float* a_sum = qkv + (size_t)T * QKV_OUT;       // T
  float* s2    = a_sum + T;                       // T
  float* sum2  = s2 + T;                          // T
  short* q2    = (short*)(sum2 + T);              // T*HID bf16 (16.8 MB)

  asum_kernel<<<T, 256, 0, stream>>>(q_act, a_sum);
  gemm_w4a8<4><<<dim3(QKV_OUT / 128, T / 128), 256, 0, stream>>>(
      q_act, w_qkv_q, act_scale, a_sum, w_qkv_scale, w_qkv_zero,
      qkv, T, QKV_OUT, HID);
  rope_kernel<<<T * (NH + NKV), 64, 0, stream>>>(qkv, positions);
  attn_kernel<<<dim3(T / 64, NH), 256, 0, stream>>>(qkv, out);   // attn -> d_out (temp)
  quant_kernel<<<T, 256, 0, stream>>>(out, q2, s2, sum2);
  gemm_w4a8<2><<<dim3(HID / 128, T / 128), 256, 0, stream>>>(
      q2, w_o_q, s2, sum2, w_o_scale, w_o_zero,
      out, T, HID, HID);
}

// Round 2
// 1260.241 us; speedup vs baseline: 1.9974x; 1.9974x over previous
//
#include <hip/hip_runtime.h>

#define T 2048
#define HID 4096
#define NH 32
#define NKV 8
#define HD 128
#define QKV_OUT ((NH + 2*NKV) * HD)   // 6144
#define SCALING 0.08838834764831843f  // 128^-0.5

typedef __attribute__((ext_vector_type(8))) short bfrag;   // 8 bf16
typedef __attribute__((ext_vector_type(4))) float ffrag;   // 4 f32 acc

__device__ __forceinline__ short f2bf(float f) {
  unsigned u = __builtin_bit_cast(unsigned, f);
  u += 0x7fffu + ((u >> 16) & 1u);   // RNE
  return (short)(u >> 16);
}

// error-free-ish bf16x2 split: x ~= hi + lo, residual ~2^-17 * |x|
__device__ __forceinline__ void split2(float x, short& hi, short& lo) {
  unsigned u = __builtin_bit_cast(unsigned, x);
  unsigned uh = u + (0x7fffu + ((u >> 16) & 1u));
  hi = (short)(uh >> 16);
  float fh = __builtin_bit_cast(float, uh & 0xffff0000u);
  float r = x - fh;                  // exact in fp32
  unsigned ur = __builtin_bit_cast(unsigned, r);
  ur += 0x7fffu + ((ur >> 16) & 1u);
  lo = (short)(ur >> 16);
}

// ---------------- a_sum: per-row int sum of q_act ----------------
__global__ __launch_bounds__(256)
void asum_kernel(const int* __restrict__ qact, float* __restrict__ a_sum) {
  __shared__ int red[256];
  const int t = blockIdx.x, tid = threadIdx.x;
  const int4* row = (const int4*)(qact + (size_t)t * HID);
  int s = 0;
#pragma unroll
  for (int i = 0; i < 4; i++) {
    int4 v = row[tid + 256 * i];
    s += v.x + v.y + v.z + v.w;
  }
  red[tid] = s; __syncthreads();
  for (int off = 128; off > 0; off >>= 1) {
    if (tid < off) red[tid] += red[tid + off];
    __syncthreads();
  }
  if (tid == 0) a_sum[t] = (float)red[0];
}

// ---------------- W4A8 GEMM: C[M,N] = sa*sw*(A·W^T - zw*asum) ----------------
// bf16 MFMA exact (small ints, fp32 acc < 2^24). 128x128 tile, BK=32.
template<int ABYTES>
__global__ __launch_bounds__(256)
void gemm_w4a8(const void* __restrict__ Av, const int* __restrict__ W,
               const float* __restrict__ s_a, const float* __restrict__ asum,
               const float* __restrict__ s_w, const float* __restrict__ z_w,
               float* __restrict__ C, int M, int N, int K) {
  __shared__ __align__(16) short As[128 * 40];
  __shared__ __align__(16) short Bs[128 * 40];
  const int tid = threadIdx.x;
  const int lane = tid & 63;
  const int quad = lane >> 4, l15 = lane & 15;
  const int wave = tid >> 6;
  const int wm = (wave >> 1) * 64, wn = (wave & 1) * 64;
  const int bm = blockIdx.y * 128, bn = blockIdx.x * 128;

  ffrag acc[4][4];
#pragma unroll
  for (int mi = 0; mi < 4; mi++)
#pragma unroll
    for (int ni = 0; ni < 4; ni++)
      acc[mi][ni] = (ffrag){0.f, 0.f, 0.f, 0.f};

  for (int k0 = 0; k0 < K; k0 += 32) {
    if constexpr (ABYTES == 4) {
      const int* A = (const int*)Av;
#pragma unroll
      for (int i = 0; i < 4; i++) {
        int e = tid + 256 * i;
        int r = e >> 3, c = e & 7;
        int4 v = *(const int4*)(A + (size_t)(bm + r) * K + k0 + c * 4);
        short4 h;
        h.x = f2bf((float)v.x); h.y = f2bf((float)v.y);
        h.z = f2bf((float)v.z); h.w = f2bf((float)v.w);
        *(short4*)&As[r * 40 + c * 4] = h;
      }
    } else {
      const short* A = (const short*)Av;
#pragma unroll
      for (int i = 0; i < 2; i++) {
        int e = tid + 256 * i;
        int r = e >> 2, c = e & 3;
        bfrag v = *(const bfrag*)(A + (size_t)(bm + r) * K + k0 + c * 8);
        *(bfrag*)&As[r * 40 + c * 8] = v;
      }
    }
#pragma unroll
    for (int i = 0; i < 4; i++) {
      int e = tid + 256 * i;
      int r = e >> 3, c = e & 7;
      int4 v = *(const int4*)(W + (size_t)(bn + r) * K + k0 + c * 4);
      short4 h;
      h.x = f2bf((float)v.x); h.y = f2bf((float)v.y);
      h.z = f2bf((float)v.z); h.w = f2bf((float)v.w);
      *(short4*)&Bs[r * 40 + c * 4] = h;
    }
    __syncthreads();

    bfrag af[4], bfv[4];
#pragma unroll
    for (int mi = 0; mi < 4; mi++)
      af[mi] = *(const bfrag*)&As[(wm + mi * 16 + l15) * 40 + quad * 8];
#pragma unroll
    for (int ni = 0; ni < 4; ni++)
      bfv[ni] = *(const bfrag*)&Bs[(wn + ni * 16 + l15) * 40 + quad * 8];
#pragma unroll
    for (int mi = 0; mi < 4; mi++)
#pragma unroll
      for (int ni = 0; ni < 4; ni++)
        acc[mi][ni] = __builtin_amdgcn_mfma_f32_16x16x32_bf16(
            af[mi], bfv[ni], acc[mi][ni], 0, 0, 0);
    __syncthreads();
  }

#pragma unroll
  for (int mi = 0; mi < 4; mi++) {
    int row0 = bm + wm + mi * 16 + quad * 4;
#pragma unroll
    for (int r = 0; r < 4; r++) {
      int row = row0 + r;
      float sa = s_a[row], av = asum[row];
#pragma unroll
      for (int ni = 0; ni < 4; ni++) {
        int col = bn + wn + ni * 16 + l15;
        C[(size_t)row * N + col] = (sa * s_w[col]) * (acc[mi][ni][r] - z_w[col] * av);
      }
    }
  }
}

// ---------------- RoPE (in-place on fp32 qkv) ----------------
__global__ __launch_bounds__(64)
void rope_kernel(float* __restrict__ qkv, const int* __restrict__ positions) {
  const int b = blockIdx.x;
  const int t = b / (NH + NKV);
  const int h = b % (NH + NKV);
  float* base = qkv + (size_t)t * QKV_OUT + (size_t)h * HD;
  const int i = threadIdx.x;
  float inv = exp2f(-0.20762050593046014f * (float)i);  // 10000^(-i/64)
  float f = (float)positions[t] * inv;
  float s, c;
  sincosf(f, &s, &c);
  float x1 = base[i], x2 = base[i + 64];
  base[i]      = x1 * c - x2 * s;
  base[i + 64] = x2 * c + x1 * s;
}

// ---------------- MFMA flash attention (causal, GQA), bf16x2-split exact ----
// Block: (head, 64 q rows). Wave w: rows q0+16w..+15. K-tile = 32 keys.
// S = Qh·Kh + Qh·Kl + Ql·Kh (3 MFMA); PV same with split P and V.
// K in LDS [key][d]; V transposed [d][key]; P round-trips LDS (C->A layout).
__global__ __launch_bounds__(256)
void attn_kernel(const float* __restrict__ qkv, float* __restrict__ attn) {
  __shared__ __align__(16) short Ks_hi[32 * 128];
  __shared__ __align__(16) short Ks_lo[32 * 128];
  __shared__ __align__(16) short Vt_hi[128 * 32];
  __shared__ __align__(16) short Vt_lo[128 * 32];
  __shared__ __align__(16) short Ps_hi[4 * 16 * 40];  // per-wave 16 rows x pitch40
  __shared__ __align__(16) short Ps_lo[4 * 16 * 40];

  const int h = blockIdx.y;
  const int qt = gridDim.x - 1 - blockIdx.x;   // heavy tiles dispatched first
  const int q0 = qt * 64;
  const int kvh = h >> 2;                      // GQA: 4 q-heads per kv head
  const int tid = threadIdx.x;
  const int lane = tid & 63;
  const int wv = tid >> 6;
  const int l15 = lane & 15, quad = lane >> 4;
  const int row_base = q0 + wv * 16;           // wave's rows row_base+0..15
  const int pw = wv * 16 * 40;

  // Q fragments for row = row_base + l15, dims kc*32 + quad*8 + j, split hi/lo
  const float* qrow = qkv + (size_t)(row_base + l15) * QKV_OUT + (size_t)h * HD;
  bfrag qh[4], ql[4];
#pragma unroll
  for (int kc = 0; kc < 4; kc++) {
    float4 f0 = *(const float4*)(qrow + kc * 32 + quad * 8);
    float4 f1 = *(const float4*)(qrow + kc * 32 + quad * 8 + 4);
    float fv[8] = {f0.x, f0.y, f0.z, f0.w, f1.x, f1.y, f1.z, f1.w};
#pragma unroll
    for (int j = 0; j < 8; j++) {
      short hi, lo; split2(fv[j], hi, lo);
      qh[kc][j] = hi; ql[kc][j] = lo;
    }
  }

  ffrag o[8];
#pragma unroll
  for (int n = 0; n < 8; n++) o[n] = (ffrag){0.f, 0.f, 0.f, 0.f};
  float m_i[4] = {-1e30f, -1e30f, -1e30f, -1e30f};
  float l_i[4] = {0.f, 0.f, 0.f, 0.f};

  const float* Kbase = qkv + (size_t)NH * HD + (size_t)kvh * HD;
  const float* Vbase = qkv + (size_t)(NH + NKV) * HD + (size_t)kvh * HD;
  const int nk = (q0 >> 5) + 2;                // keys 0 .. q0+63

  for (int kt = 0; kt < nk; kt++) {
    const int k0 = kt << 5;
    __syncthreads();                           // LDS reuse from prev tile
    // ---- stage K [key][d] hi/lo ----
#pragma unroll
    for (int i = 0; i < 4; i++) {
      int e = tid + 256 * i;
      int k = e >> 5, dc = e & 31;             // key, dim-chunk(4)
      float4 f = *(const float4*)(Kbase + (size_t)(k0 + k) * QKV_OUT + dc * 4);
      short4 h4, l4;
      split2(f.x, h4.x, l4.x); split2(f.y, h4.y, l4.y);
      split2(f.z, h4.z, l4.z); split2(f.w, h4.w, l4.w);
      *(short4*)&Ks_hi[k * 128 + dc * 4] = h4;
      *(short4*)&Ks_lo[k * 128 + dc * 4] = l4;
    }
    // ---- stage V transposed [d][key] hi/lo ----
#pragma unroll
    for (int i = 0; i < 4; i++) {
      int e = tid + 256 * i;
      int k = e & 31, dc = e >> 5;             // key, dim-chunk(4)
      float4 f = *(const float4*)(Vbase + (size_t)(k0 + k) * QKV_OUT + dc * 4);
      short hi, lo;
      split2(f.x, hi, lo); Vt_hi[(dc*4+0)*32 + k] = hi; Vt_lo[(dc*4+0)*32 + k] = lo;
      split2(f.y, hi, lo); Vt_hi[(dc*4+1)*32 + k] = hi; Vt_lo[(dc*4+1)*32 + k] = lo;
      split2(f.z, hi, lo); Vt_hi[(dc*4+2)*32 + k] = hi; Vt_lo[(dc*4+2)*32 + k] = lo;
      split2(f.w, hi, lo); Vt_hi[(dc*4+3)*32 + k] = hi; Vt_lo[(dc*4+3)*32 + k] = lo;
    }
    __syncthreads();

    if (k0 <= row_base + 15) {                 // wave has unmasked rows
      // ---- S = Q·K^T (split x3) ----
      ffrag s[2];
      s[0] = (ffrag){0.f,0.f,0.f,0.f}; s[1] = (ffrag){0.f,0.f,0.f,0.f};
#pragma unroll
      for (int n = 0; n < 2; n++) {
#pragma unroll
        for (int kc = 0; kc < 4; kc++) {
          bfrag bh = *(const bfrag*)&Ks_hi[(n*16 + l15) * 128 + kc*32 + quad*8];
          bfrag bl = *(const bfrag*)&Ks_lo[(n*16 + l15) * 128 + kc*32 + quad*8];
          s[n] = __builtin_amdgcn_mfma_f32_16x16x32_bf16(qh[kc], bh, s[n], 0,0,0);
          s[n] = __builtin_amdgcn_mfma_f32_16x16x32_bf16(qh[kc], bl, s[n], 0,0,0);
          s[n] = __builtin_amdgcn_mfma_f32_16x16x32_bf16(ql[kc], bh, s[n], 0,0,0);
        }
      }
      // ---- online softmax ----
      const bool full = (k0 + 31 <= row_base);
      float sv[2][4];
#pragma unroll
      for (int n = 0; n < 2; n++)
#pragma unroll
        for (int r = 0; r < 4; r++) {
          float v = s[n][r] * SCALING;
          if (!full) {
            int key = k0 + n * 16 + l15;
            int row = row_base + quad * 4 + r;
            if (key > row) v = -1e30f;
          }
          sv[n][r] = v;
        }
      float alpha[4], ls[4];
#pragma unroll
      for (int r = 0; r < 4; r++) {
        float mt = fmaxf(sv[0][r], sv[1][r]);
        mt = fmaxf(mt, __shfl_xor(mt, 1));
        mt = fmaxf(mt, __shfl_xor(mt, 2));
        mt = fmaxf(mt, __shfl_xor(mt, 4));
        mt = fmaxf(mt, __shfl_xor(mt, 8));
        float m_new = fmaxf(m_i[r], mt);
        alpha[r] = __expf(m_i[r] - m_new);
        m_i[r] = m_new;
        ls[r] = 0.f;
      }
#pragma unroll
      for (int n = 0; n < 2; n++)
#pragma unroll
        for (int r = 0; r < 4; r++) {
          float p = __expf(sv[n][r] - m_i[r]);
          ls[r] += p;
          short hi, lo; split2(p, hi, lo);
          Ps_hi[pw + (quad*4 + r) * 40 + n*16 + l15] = hi;
          Ps_lo[pw + (quad*4 + r) * 40 + n*16 + l15] = lo;
        }
#pragma unroll
      for (int r = 0; r < 4; r++) {
        float t2 = ls[r];
        t2 += __shfl_xor(t2, 1); t2 += __shfl_xor(t2, 2);
        t2 += __shfl_xor(t2, 4); t2 += __shfl_xor(t2, 8);
        l_i[r] = l_i[r] * alpha[r] + t2;
      }
      // rescale O
#pragma unroll
      for (int n = 0; n < 8; n++)
#pragma unroll
        for (int r = 0; r < 4; r++) o[n][r] *= alpha[r];
      // ---- PV (split x3); P frag read back in A layout (same wave, no barrier)
      bfrag ph = *(const bfrag*)&Ps_hi[pw + l15 * 40 + quad * 8];
      bfrag pl = *(const bfrag*)&Ps_lo[pw + l15 * 40 + quad * 8];
#pragma unroll
      for (int n = 0; n < 8; n++) {
        bfrag vh = *(const bfrag*)&Vt_hi[(n*16 + l15) * 32 + quad * 8];
        bfrag vl = *(const bfrag*)&Vt_lo[(n*16 + l15) * 32 + quad * 8];
        o[n] = __builtin_amdgcn_mfma_f32_16x16x32_bf16(ph, vh, o[n], 0,0,0);
        o[n] = __builtin_amdgcn_mfma_f32_16x16x32_bf16(ph, vl, o[n], 0,0,0);
        o[n] = __builtin_amdgcn_mfma_f32_16x16x32_bf16(pl, vh, o[n], 0,0,0);
      }
    }
  }

  // epilogue: O C-layout col=n*16+l15, row=quad*4+r
  float inv[4];
#pragma unroll
  for (int r = 0; r < 4; r++) inv[r] = 1.f / l_i[r];
#pragma unroll
  for (int n = 0; n < 8; n++)
#pragma unroll
    for (int r = 0; r < 4; r++) {
      int row = row_base + quad * 4 + r;
      attn[(size_t)row * HID + (size_t)h * HD + n * 16 + l15] = o[n][r] * inv[r];
    }
}

// ---------------- dynamic quant with sum (per row) ----------------
__global__ __launch_bounds__(256)
void quant_kernel(const float* __restrict__ x, short* __restrict__ q2,
                  float* __restrict__ s2, float* __restrict__ sum2) {
  __shared__ float red[256];
  const int t = blockIdx.x, tid = threadIdx.x;
  const float* row = x + (size_t)t * HID;
  float4 v[4];
  float m = 0.f;
#pragma unroll
  for (int i = 0; i < 4; i++) {
    v[i] = *(const float4*)(row + (tid + 256 * i) * 4);
    m = fmaxf(m, fmaxf(fmaxf(fabsf(v[i].x), fabsf(v[i].y)),
                       fmaxf(fabsf(v[i].z), fabsf(v[i].w))));
  }
  red[tid] = m; __syncthreads();
  for (int off = 128; off > 0; off >>= 1) {
    if (tid < off) red[tid] = fmaxf(red[tid], red[tid + off]);
    __syncthreads();
  }
  float s = fmaxf(red[0], 1e-8f) / 127.f;
  __syncthreads();
  float ssum = 0.f;
#pragma unroll
  for (int i = 0; i < 4; i++) {
    short4 h; float q;
    q = fminf(127.f, fmaxf(-127.f, rintf(v[i].x / s))); ssum += q; h.x = f2bf(q);
    q = fminf(127.f, fmaxf(-127.f, rintf(v[i].y / s))); ssum += q; h.y = f2bf(q);
    q = fminf(127.f, fmaxf(-127.f, rintf(v[i].z / s))); ssum += q; h.z = f2bf(q);
    q = fminf(127.f, fmaxf(-127.f, rintf(v[i].w / s))); ssum += q; h.w = f2bf(q);
    *(short4*)(q2 + (size_t)t * HID + (tid + 256 * i) * 4) = h;
  }
  red[tid] = ssum; __syncthreads();
  for (int off = 128; off > 0; off >>= 1) {
    if (tid < off) red[tid] += red[tid + off];
    __syncthreads();
  }
  if (tid == 0) { s2[t] = s; sum2[t] = red[0]; }
}

// ---------------- launch ----------------
extern "C" void kernel_launch(void* const* d_in, const int* in_sizes, int n_in,
                              void* d_out, int out_size, void* d_ws, size_t ws_size,
                              hipStream_t stream) {
  const int*   positions   = (const int*)d_in[0];
  const int*   q_act       = (const int*)d_in[1];
  const float* act_scale   = (const float*)d_in[2];
  const int*   w_qkv_q     = (const int*)d_in[3];
  const float* w_qkv_scale = (const float*)d_in[4];
  const float* w_qkv_zero  = (const float*)d_in[5];
  const int*   w_o_q       = (const int*)d_in[6];
  const float* w_o_scale   = (const float*)d_in[7];
  const float* w_o_zero    = (const float*)d_in[8];
  float* out = (float*)d_out;

  float* qkv   = (float*)d_ws;                    // T*6144 f32
  float* a_sum = qkv + (size_t)T * QKV_OUT;
  float* s2    = a_sum + T;
  float* sum2  = s2 + T;
  short* q2    = (short*)(sum2 + T);              // T*HID bf16

  asum_kernel<<<T, 256, 0, stream>>>(q_act, a_sum);
  gemm_w4a8<4><<<dim3(QKV_OUT / 128, T / 128), 256, 0, stream>>>(
      q_act, w_qkv_q, act_scale, a_sum, w_qkv_scale, w_qkv_zero,
      qkv, T, QKV_OUT, HID);
  rope_kernel<<<T * (NH + NKV), 64, 0, stream>>>(qkv, positions);
  attn_kernel<<<dim3(T / 64, NH), 256, 0, stream>>>(qkv, out);
  quant_kernel<<<T, 256, 0, stream>>>(out, q2, s2, sum2);
  gemm_w4a8<2><<<dim3(HID / 128, T / 128), 256, 0, stream>>>(
      q2, w_o_q, s2, sum2, w_o_scale, w_o_zero,
      out, T, HID, HID);
}

// Round 3
// 918.041 us; speedup vs baseline: 2.7419x; 1.3728x over previous
//
#include <hip/hip_runtime.h>

#define T 2048
#define HID 4096
#define NH 32
#define NKV 8
#define HD 128
#define QKV_OUT ((NH + 2*NKV) * HD)   // 6144
#define SCALING 0.08838834764831843f  // 128^-0.5

typedef __attribute__((ext_vector_type(8))) short bfrag;   // 8 bf16
typedef __attribute__((ext_vector_type(4))) float ffrag;   // 4 f32 acc

__device__ __forceinline__ short f2bf(float f) {
  unsigned u = __builtin_bit_cast(unsigned, f);
  u += 0x7fffu + ((u >> 16) & 1u);   // RNE; exact for ints <= 255
  return (short)(u >> 16);
}

// bf16x2 split: x ~= hi + lo, residual ~2^-17 * |x|
__device__ __forceinline__ void split2(float x, short& hi, short& lo) {
  unsigned u = __builtin_bit_cast(unsigned, x);
  unsigned uh = u + (0x7fffu + ((u >> 16) & 1u));
  hi = (short)(uh >> 16);
  float fh = __builtin_bit_cast(float, uh & 0xffff0000u);
  float r = x - fh;                  // exact in fp32
  unsigned ur = __builtin_bit_cast(unsigned, r);
  ur += 0x7fffu + ((ur >> 16) & 1u);
  lo = (short)(ur >> 16);
}

// ---------------- a_sum ----------------
__global__ __launch_bounds__(256)
void asum_kernel(const int* __restrict__ qact, float* __restrict__ a_sum) {
  __shared__ int red[256];
  const int t = blockIdx.x, tid = threadIdx.x;
  const int4* row = (const int4*)(qact + (size_t)t * HID);
  int s = 0;
#pragma unroll
  for (int i = 0; i < 4; i++) {
    int4 v = row[tid + 256 * i];
    s += v.x + v.y + v.z + v.w;
  }
  red[tid] = s; __syncthreads();
  for (int off = 128; off > 0; off >>= 1) {
    if (tid < off) red[tid] += red[tid + off];
    __syncthreads();
  }
  if (tid == 0) a_sum[t] = (float)red[0];
}

// ---------------- int32 -> bf16 (exact for |v|<=255) ----------------
__global__ __launch_bounds__(256)
void conv_i2b(const int* __restrict__ src, short* __restrict__ dst, int n8) {
  int idx = blockIdx.x * 256 + threadIdx.x;
  if (idx >= n8) return;
  const int4* s4 = (const int4*)src + (size_t)idx * 2;
  int4 a = s4[0], b = s4[1];
  bfrag h;
  h[0] = f2bf((float)a.x); h[1] = f2bf((float)a.y);
  h[2] = f2bf((float)a.z); h[3] = f2bf((float)a.w);
  h[4] = f2bf((float)b.x); h[5] = f2bf((float)b.y);
  h[6] = f2bf((float)b.z); h[7] = f2bf((float)b.w);
  *(bfrag*)(dst + (size_t)idx * 8) = h;
}

// ---------------- W4A8 GEMM: C = sa*sw*(A*W^T - zw*asum) ----------------
// A: M x K bf16. W: N x K (bf16 if WBF, else int32 converted in-kernel).
template<bool WBF>
__global__ __launch_bounds__(256)
void gemm_w4a8(const short* __restrict__ A, const void* __restrict__ Wv,
               const float* __restrict__ s_a, const float* __restrict__ asum,
               const float* __restrict__ s_w, const float* __restrict__ z_w,
               float* __restrict__ C, int M, int N, int K) {
  __shared__ __align__(16) short As[128 * 40];
  __shared__ __align__(16) short Bs[128 * 40];
  const int tid = threadIdx.x;
  const int lane = tid & 63;
  const int quad = lane >> 4, l15 = lane & 15;
  const int wave = tid >> 6;
  const int wm = (wave >> 1) * 64, wn = (wave & 1) * 64;
  const int bm = blockIdx.y * 128, bn = blockIdx.x * 128;

  ffrag acc[4][4];
#pragma unroll
  for (int mi = 0; mi < 4; mi++)
#pragma unroll
    for (int ni = 0; ni < 4; ni++)
      acc[mi][ni] = (ffrag){0.f, 0.f, 0.f, 0.f};

  for (int k0 = 0; k0 < K; k0 += 32) {
#pragma unroll
    for (int i = 0; i < 2; i++) {
      int e = tid + 256 * i;
      int r = e >> 2, c = e & 3;
      *(bfrag*)&As[r * 40 + c * 8] =
          *(const bfrag*)(A + (size_t)(bm + r) * K + k0 + c * 8);
    }
    if constexpr (WBF) {
      const short* W = (const short*)Wv;
#pragma unroll
      for (int i = 0; i < 2; i++) {
        int e = tid + 256 * i;
        int r = e >> 2, c = e & 3;
        *(bfrag*)&Bs[r * 40 + c * 8] =
            *(const bfrag*)(W + (size_t)(bn + r) * K + k0 + c * 8);
      }
    } else {
      const int* W = (const int*)Wv;
#pragma unroll
      for (int i = 0; i < 4; i++) {
        int e = tid + 256 * i;
        int r = e >> 3, c = e & 7;
        int4 v = *(const int4*)(W + (size_t)(bn + r) * K + k0 + c * 4);
        short4 h;
        h.x = f2bf((float)v.x); h.y = f2bf((float)v.y);
        h.z = f2bf((float)v.z); h.w = f2bf((float)v.w);
        *(short4*)&Bs[r * 40 + c * 4] = h;
      }
    }
    __syncthreads();

    bfrag af[4], bfv[4];
#pragma unroll
    for (int mi = 0; mi < 4; mi++)
      af[mi] = *(const bfrag*)&As[(wm + mi * 16 + l15) * 40 + quad * 8];
#pragma unroll
    for (int ni = 0; ni < 4; ni++)
      bfv[ni] = *(const bfrag*)&Bs[(wn + ni * 16 + l15) * 40 + quad * 8];
#pragma unroll
    for (int mi = 0; mi < 4; mi++)
#pragma unroll
      for (int ni = 0; ni < 4; ni++)
        acc[mi][ni] = __builtin_amdgcn_mfma_f32_16x16x32_bf16(
            af[mi], bfv[ni], acc[mi][ni], 0, 0, 0);
    __syncthreads();
  }

#pragma unroll
  for (int mi = 0; mi < 4; mi++) {
    int row0 = bm + wm + mi * 16 + quad * 4;
#pragma unroll
    for (int r = 0; r < 4; r++) {
      int row = row0 + r;
      float sa = s_a[row], av = asum[row];
#pragma unroll
      for (int ni = 0; ni < 4; ni++) {
        int col = bn + wn + ni * 16 + l15;
        C[(size_t)row * N + col] = (sa * s_w[col]) * (acc[mi][ni][r] - z_w[col] * av);
      }
    }
  }
}

// ---------------- RoPE (in-place) ----------------
__global__ __launch_bounds__(64)
void rope_kernel(float* __restrict__ qkv, const int* __restrict__ positions) {
  const int b = blockIdx.x;
  const int t = b / (NH + NKV);
  const int h = b % (NH + NKV);
  float* base = qkv + (size_t)t * QKV_OUT + (size_t)h * HD;
  const int i = threadIdx.x;
  float inv = exp2f(-0.20762050593046014f * (float)i);  // 10000^(-i/64)
  float f = (float)positions[t] * inv;
  float s, c;
  sincosf(f, &s, &c);
  float x1 = base[i], x2 = base[i + 64];
  base[i]      = x1 * c - x2 * s;
  base[i + 64] = x2 * c + x1 * s;
}

// ---------------- split K/V into bf16 hi/lo; V transposed ----------------
// Kh/Kl: [NKV][T][HD]. Vth/Vtl: [NKV][HD][T].
__global__ __launch_bounds__(256)
void split_kv(const float* __restrict__ qkv,
              short* __restrict__ Kh, short* __restrict__ Kl,
              short* __restrict__ Vth, short* __restrict__ Vtl) {
  __shared__ __align__(16) short Vh_lds[128 * 72];
  __shared__ __align__(16) short Vl_lds[128 * 72];
  const int kvh = blockIdx.y;
  const int t0 = blockIdx.x * 64;
  const int tid = threadIdx.x;
  // K
#pragma unroll
  for (int i = 0; i < 8; i++) {
    int c = tid + 256 * i;
    int key = c >> 5, dc = c & 31;
    float4 f = *(const float4*)(qkv + (size_t)(t0 + key) * QKV_OUT
                                + (size_t)NH * HD + (size_t)kvh * HD + dc * 4);
    short4 h4, l4;
    split2(f.x, h4.x, l4.x); split2(f.y, h4.y, l4.y);
    split2(f.z, h4.z, l4.z); split2(f.w, h4.w, l4.w);
    size_t o = (size_t)kvh * T * HD + (size_t)(t0 + key) * HD + dc * 4;
    *(short4*)(Kh + o) = h4;
    *(short4*)(Kl + o) = l4;
  }
  // V -> LDS transposed
#pragma unroll
  for (int i = 0; i < 8; i++) {
    int c = tid + 256 * i;
    int key = c >> 5, dc = c & 31;
    float4 f = *(const float4*)(qkv + (size_t)(t0 + key) * QKV_OUT
                                + (size_t)(NH + NKV) * HD + (size_t)kvh * HD + dc * 4);
    short hi, lo;
    split2(f.x, hi, lo); Vh_lds[(dc*4+0)*72 + key] = hi; Vl_lds[(dc*4+0)*72 + key] = lo;
    split2(f.y, hi, lo); Vh_lds[(dc*4+1)*72 + key] = hi; Vl_lds[(dc*4+1)*72 + key] = lo;
    split2(f.z, hi, lo); Vh_lds[(dc*4+2)*72 + key] = hi; Vl_lds[(dc*4+2)*72 + key] = lo;
    split2(f.w, hi, lo); Vh_lds[(dc*4+3)*72 + key] = hi; Vl_lds[(dc*4+3)*72 + key] = lo;
  }
  __syncthreads();
#pragma unroll
  for (int i = 0; i < 4; i++) {
    int c = tid + 256 * i;
    int row = c >> 3, cc = c & 7;
    size_t o = (size_t)kvh * HD * T + (size_t)row * T + t0 + cc * 8;
    *(bfrag*)(Vth + o) = *(const bfrag*)&Vh_lds[row * 72 + cc * 8];
    *(bfrag*)(Vtl + o) = *(const bfrag*)&Vl_lds[row * 72 + cc * 8];
  }
}

// ---------------- MFMA flash attention ----------------
// Block: (kv-head, 16 q rows). Wave wv handles q-head kvh*4+wv, same rows.
// K/V staged once per block, shared by 4 heads. S and PV use bf16x2 3-MFMA.
__global__ __launch_bounds__(256)
void attn_kernel(const float* __restrict__ qkv,
                 const short* __restrict__ Kh, const short* __restrict__ Kl,
                 const short* __restrict__ Vth, const short* __restrict__ Vtl,
                 float* __restrict__ attn) {
  __shared__ __align__(16) short Ksh[32 * 136];   // pitch 136: +4 banks/row
  __shared__ __align__(16) short Ksl[32 * 136];
  __shared__ __align__(16) short Vsh[128 * 40];   // pitch 40: +20 banks/row
  __shared__ __align__(16) short Vsl[128 * 40];
  __shared__ __align__(16) short Psh[4 * 16 * 40];
  __shared__ __align__(16) short Psl[4 * 16 * 40];

  const int kvh = blockIdx.y;
  const int qt = gridDim.x - 1 - blockIdx.x;   // heavy first
  const int q0 = qt * 16;
  const int tid = threadIdx.x;
  const int lane = tid & 63;
  const int wv = tid >> 6;
  const int l15 = lane & 15, quad = lane >> 4;
  const int h = kvh * 4 + wv;
  const int pw = wv * 16 * 40;

  // Q fragment: row q0+l15 of head h, dims kc*32+quad*8+j
  const float* qrow = qkv + (size_t)(q0 + l15) * QKV_OUT + (size_t)h * HD;
  bfrag qh[4], ql[4];
#pragma unroll
  for (int kc = 0; kc < 4; kc++) {
    float4 f0 = *(const float4*)(qrow + kc * 32 + quad * 8);
    float4 f1 = *(const float4*)(qrow + kc * 32 + quad * 8 + 4);
    float fv[8] = {f0.x, f0.y, f0.z, f0.w, f1.x, f1.y, f1.z, f1.w};
#pragma unroll
    for (int j = 0; j < 8; j++) {
      short hi, lo; split2(fv[j], hi, lo);
      qh[kc][j] = hi; ql[kc][j] = lo;
    }
  }

  ffrag o[8];
#pragma unroll
  for (int n = 0; n < 8; n++) o[n] = (ffrag){0.f, 0.f, 0.f, 0.f};
  float m_i[4] = {-1e30f, -1e30f, -1e30f, -1e30f};
  float l_i[4] = {0.f, 0.f, 0.f, 0.f};

  const short* KhB = Kh + (size_t)kvh * T * HD;
  const short* KlB = Kl + (size_t)kvh * T * HD;
  const short* VhB = Vth + (size_t)kvh * HD * T;
  const short* VlB = Vtl + (size_t)kvh * HD * T;
  const int nk = ((q0 + 15) >> 5) + 1;         // keys 0..q0+15

  for (int kt = 0; kt < nk; kt++) {
    const int k0 = kt << 5;
    __syncthreads();
    // stage K [key][d] hi/lo — pure b128 copies
#pragma unroll
    for (int i = 0; i < 2; i++) {
      int c = tid + 256 * i;
      int r = c >> 4, cc = c & 15;
      *(bfrag*)&Ksh[r * 136 + cc * 8] = *(const bfrag*)(KhB + (size_t)(k0 + r) * HD + cc * 8);
      *(bfrag*)&Ksl[r * 136 + cc * 8] = *(const bfrag*)(KlB + (size_t)(k0 + r) * HD + cc * 8);
    }
    // stage V [d][key] hi/lo
#pragma unroll
    for (int i = 0; i < 2; i++) {
      int c = tid + 256 * i;
      int d = c >> 2, cc = c & 3;
      *(bfrag*)&Vsh[d * 40 + cc * 8] = *(const bfrag*)(VhB + (size_t)d * T + k0 + cc * 8);
      *(bfrag*)&Vsl[d * 40 + cc * 8] = *(const bfrag*)(VlB + (size_t)d * T + k0 + cc * 8);
    }
    __syncthreads();

    // ---- S = Q K^T (3 MFMA per split pair) ----
    ffrag s[2];
    s[0] = (ffrag){0.f,0.f,0.f,0.f}; s[1] = (ffrag){0.f,0.f,0.f,0.f};
#pragma unroll
    for (int n = 0; n < 2; n++) {
#pragma unroll
      for (int kc = 0; kc < 4; kc++) {
        bfrag bh = *(const bfrag*)&Ksh[(n*16 + l15) * 136 + kc*32 + quad*8];
        bfrag bl = *(const bfrag*)&Ksl[(n*16 + l15) * 136 + kc*32 + quad*8];
        s[n] = __builtin_amdgcn_mfma_f32_16x16x32_bf16(qh[kc], bh, s[n], 0,0,0);
        s[n] = __builtin_amdgcn_mfma_f32_16x16x32_bf16(qh[kc], bl, s[n], 0,0,0);
        s[n] = __builtin_amdgcn_mfma_f32_16x16x32_bf16(ql[kc], bh, s[n], 0,0,0);
      }
    }
    // ---- online softmax ----
    const bool full = (k0 + 31 <= q0);
    float sv[2][4];
#pragma unroll
    for (int n = 0; n < 2; n++)
#pragma unroll
      for (int r = 0; r < 4; r++) {
        float v = s[n][r] * SCALING;
        if (!full) {
          int key = k0 + n * 16 + l15;
          int row = q0 + quad * 4 + r;
          if (key > row) v = -1e30f;
        }
        sv[n][r] = v;
      }
    float alpha[4], ls[4];
#pragma unroll
    for (int r = 0; r < 4; r++) {
      float mt = fmaxf(sv[0][r], sv[1][r]);
      mt = fmaxf(mt, __shfl_xor(mt, 1));
      mt = fmaxf(mt, __shfl_xor(mt, 2));
      mt = fmaxf(mt, __shfl_xor(mt, 4));
      mt = fmaxf(mt, __shfl_xor(mt, 8));
      float m_new = fmaxf(m_i[r], mt);
      alpha[r] = __expf(m_i[r] - m_new);
      m_i[r] = m_new;
      ls[r] = 0.f;
    }
#pragma unroll
    for (int n = 0; n < 2; n++)
#pragma unroll
      for (int r = 0; r < 4; r++) {
        float p = __expf(sv[n][r] - m_i[r]);
        ls[r] += p;
        short hi, lo; split2(p, hi, lo);
        Psh[pw + (quad*4 + r) * 40 + n*16 + l15] = hi;
        Psl[pw + (quad*4 + r) * 40 + n*16 + l15] = lo;
      }
#pragma unroll
    for (int r = 0; r < 4; r++) {
      float t2 = ls[r];
      t2 += __shfl_xor(t2, 1); t2 += __shfl_xor(t2, 2);
      t2 += __shfl_xor(t2, 4); t2 += __shfl_xor(t2, 8);
      l_i[r] = l_i[r] * alpha[r] + t2;
    }
#pragma unroll
    for (int n = 0; n < 8; n++)
#pragma unroll
      for (int r = 0; r < 4; r++) o[n][r] *= alpha[r];
    // ---- PV ---- (P read back in A layout; same wave wrote it, no barrier)
    bfrag ph = *(const bfrag*)&Psh[pw + l15 * 40 + quad * 8];
    bfrag pl = *(const bfrag*)&Psl[pw + l15 * 40 + quad * 8];
#pragma unroll
    for (int n = 0; n < 8; n++) {
      bfrag vh = *(const bfrag*)&Vsh[(n*16 + l15) * 40 + quad * 8];
      bfrag vl = *(const bfrag*)&Vsl[(n*16 + l15) * 40 + quad * 8];
      o[n] = __builtin_amdgcn_mfma_f32_16x16x32_bf16(ph, vh, o[n], 0,0,0);
      o[n] = __builtin_amdgcn_mfma_f32_16x16x32_bf16(ph, vl, o[n], 0,0,0);
      o[n] = __builtin_amdgcn_mfma_f32_16x16x32_bf16(pl, vh, o[n], 0,0,0);
    }
  }

  float inv[4];
#pragma unroll
  for (int r = 0; r < 4; r++) inv[r] = 1.f / l_i[r];
#pragma unroll
  for (int n = 0; n < 8; n++)
#pragma unroll
    for (int r = 0; r < 4; r++) {
      int row = q0 + quad * 4 + r;
      attn[(size_t)row * HID + (size_t)h * HD + n * 16 + l15] = o[n][r] * inv[r];
    }
}

// ---------------- dynamic quant with sum ----------------
__global__ __launch_bounds__(256)
void quant_kernel(const float* __restrict__ x, short* __restrict__ q2,
                  float* __restrict__ s2, float* __restrict__ sum2) {
  __shared__ float red[256];
  const int t = blockIdx.x, tid = threadIdx.x;
  const float* row = x + (size_t)t * HID;
  float4 v[4];
  float m = 0.f;
#pragma unroll
  for (int i = 0; i < 4; i++) {
    v[i] = *(const float4*)(row + (tid + 256 * i) * 4);
    m = fmaxf(m, fmaxf(fmaxf(fabsf(v[i].x), fabsf(v[i].y)),
                       fmaxf(fabsf(v[i].z), fabsf(v[i].w))));
  }
  red[tid] = m; __syncthreads();
  for (int off = 128; off > 0; off >>= 1) {
    if (tid < off) red[tid] = fmaxf(red[tid], red[tid + off]);
    __syncthreads();
  }
  float s = fmaxf(red[0], 1e-8f) / 127.f;
  __syncthreads();
  float ssum = 0.f;
#pragma unroll
  for (int i = 0; i < 4; i++) {
    short4 h; float q;
    q = fminf(127.f, fmaxf(-127.f, rintf(v[i].x / s))); ssum += q; h.x = f2bf(q);
    q = fminf(127.f, fmaxf(-127.f, rintf(v[i].y / s))); ssum += q; h.y = f2bf(q);
    q = fminf(127.f, fmaxf(-127.f, rintf(v[i].z / s))); ssum += q; h.z = f2bf(q);
    q = fminf(127.f, fmaxf(-127.f, rintf(v[i].w / s))); ssum += q; h.w = f2bf(q);
    *(short4*)(q2 + (size_t)t * HID + (tid + 256 * i) * 4) = h;
  }
  red[tid] = ssum; __syncthreads();
  for (int off = 128; off > 0; off >>= 1) {
    if (tid < off) red[tid] += red[tid + off];
    __syncthreads();
  }
  if (tid == 0) { s2[t] = s; sum2[t] = red[0]; }
}

// ---------------- launch ----------------
extern "C" void kernel_launch(void* const* d_in, const int* in_sizes, int n_in,
                              void* d_out, int out_size, void* d_ws, size_t ws_size,
                              hipStream_t stream) {
  const int*   positions   = (const int*)d_in[0];
  const int*   q_act       = (const int*)d_in[1];
  const float* act_scale   = (const float*)d_in[2];
  const int*   w_qkv_q     = (const int*)d_in[3];
  const float* w_qkv_scale = (const float*)d_in[4];
  const float* w_qkv_zero  = (const float*)d_in[5];
  const int*   w_o_q       = (const int*)d_in[6];
  const float* w_o_scale   = (const float*)d_in[7];
  const float* w_o_zero    = (const float*)d_in[8];
  float* out = (float*)d_out;

  size_t off = 0;
  auto alloc = [&](size_t bytes) -> void* {
    void* p = (char*)d_ws + off;
    off += (bytes + 255) & ~(size_t)255;
    return p;
  };
  float* qkv   = (float*)alloc((size_t)T * QKV_OUT * 4);
  short* a_bf  = (short*)alloc((size_t)T * HID * 2);
  short* q2    = (short*)alloc((size_t)T * HID * 2);
  short* Kh    = (short*)alloc((size_t)NKV * T * HD * 2);
  short* Kl    = (short*)alloc((size_t)NKV * T * HD * 2);
  short* Vth   = (short*)alloc((size_t)NKV * T * HD * 2);
  short* Vtl   = (short*)alloc((size_t)NKV * T * HD * 2);
  float* a_sum = (float*)alloc(T * 4);
  float* s2    = (float*)alloc(T * 4);
  float* sum2  = (float*)alloc(T * 4);
  short* wqkv_bf = (short*)alloc((size_t)QKV_OUT * HID * 2);
  short* wo_bf   = (short*)alloc((size_t)HID * HID * 2);
  const bool wconv = (ws_size >= off);   // constant across calls

  asum_kernel<<<T, 256, 0, stream>>>(q_act, a_sum);
  conv_i2b<<<(T * HID / 8 + 255) / 256, 256, 0, stream>>>(q_act, a_bf, T * HID / 8);
  if (wconv) {
    conv_i2b<<<(QKV_OUT * HID / 8 + 255) / 256, 256, 0, stream>>>(w_qkv_q, wqkv_bf, QKV_OUT * HID / 8);
    conv_i2b<<<(HID * HID / 8 + 255) / 256, 256, 0, stream>>>(w_o_q, wo_bf, HID * HID / 8);
    gemm_w4a8<true><<<dim3(QKV_OUT / 128, T / 128), 256, 0, stream>>>(
        a_bf, wqkv_bf, act_scale, a_sum, w_qkv_scale, w_qkv_zero, qkv, T, QKV_OUT, HID);
  } else {
    gemm_w4a8<false><<<dim3(QKV_OUT / 128, T / 128), 256, 0, stream>>>(
        a_bf, w_qkv_q, act_scale, a_sum, w_qkv_scale, w_qkv_zero, qkv, T, QKV_OUT, HID);
  }
  rope_kernel<<<T * (NH + NKV), 64, 0, stream>>>(qkv, positions);
  split_kv<<<dim3(T / 64, NKV), 256, 0, stream>>>(qkv, Kh, Kl, Vth, Vtl);
  attn_kernel<<<dim3(T / 16, NKV), 256, 0, stream>>>(qkv, Kh, Kl, Vth, Vtl, out);
  quant_kernel<<<T, 256, 0, stream>>>(out, q2, s2, sum2);
  if (wconv) {
    gemm_w4a8<true><<<dim3(HID / 128, T / 128), 256, 0, stream>>>(
        q2, wo_bf, s2, sum2, w_o_scale, w_o_zero, out, T, HID, HID);
  } else {
    gemm_w4a8<false><<<dim3(HID / 128, T / 128), 256, 0, stream>>>(
        q2, w_o_q, s2, sum2, w_o_scale, w_o_zero, out, T, HID, HID);
  }
}